// Round 5
// baseline (193.047 us; speedup 1.0000x reference)
//
#include <hip/hip_runtime.h>

#define B_  8
#define LV_ 4096
#define D_  256
#define N_  2048
#define P_  32

typedef float v4f __attribute__((ext_vector_type(4)));

__device__ __forceinline__ float lane_bcast_f(float v, int l) {
    return __int_as_float(__builtin_amdgcn_readlane(__float_as_int(v), l));
}

// Pass 1: counting-sort box ids by batch into order[] (d_ws) for XCD-L2 locality.
__global__ __launch_bounds__(256) void build_order_kernel(
    const int* __restrict__ batch_idx, int* __restrict__ order)
{
    __shared__ int cnt[B_], cur[B_];
    const int tid = threadIdx.x;
    if (tid < B_) cnt[tid] = 0;
    __syncthreads();
    for (int n = tid; n < N_; n += 256) atomicAdd(&cnt[batch_idx[n]], 1);
    __syncthreads();
    if (tid == 0) {
        int s = 0;
        for (int b = 0; b < B_; ++b) { cur[b] = s; s += cnt[b]; }
    }
    __syncthreads();
    for (int n = tid; n < N_; n += 256)
        order[atomicAdd(&cur[batch_idx[n]], 1)] = n;
}

// Pass 2: one wave per (box, bin), 4 waves per block.
//
// R1: lane-parallel closed-form weights (2nd difference of prefix area).
// R2: bijective XCD swizzle (FETCH 212->57MB) + packed f32 FMA.      [124us]
// R3: FAILED (134us): clamp-indexed loads -> per-load VALU addr math + occupancy cap.
// R4: FAILED (127us): rows 4..7 imm offsets (4096..7168B) exceed the 13-bit
//     signed global imm (+-4096) -> compiler emitted v_lshl_add_u64 per load;
//     base ptr per-lane -> VGPR-pair adds. VALU 33->47%, pipeline gain eaten.
// R5: SCALAR ADDRESSING (HK readfirstlane->SGPR technique) + clean pipeline:
//     - n is block-uniform, r_first wave-uniform -> readfirstlane them; all
//       row bases become SGPR, loads are global_load_dwordx4 v,voff,s[base]
//       with imm offsets {0,1024,2048,3072}; pointer bumps are SALU.
//     - A/B 4-row double-buffer on separate scalar bases 4KB apart: >=4 loads
//       outstanding through every FMA phase.
//     - acc0/acc1 split halves the pk_fma dependency chain.
//     - per-row VALU: 1 v_readlane + 2 v_pk_fma_f32 only.
__global__ __launch_bounds__(256) void roi_rows_kernel(
    const float* __restrict__ feat,       // [B, LV, D]
    const float* __restrict__ boxes,      // [N, 2]
    const int*   __restrict__ batch_idx,  // [N]
    const int*   __restrict__ order,      // [N] sorted by batch
    float*       __restrict__ out)        // [N, P, D]
{
    const int nwg = (N_ * P_) / 4;            // 16384 blocks
    const int cpx = nwg >> 3;                 // 2048 blocks per XCD chunk
    const int bid = blockIdx.x;
    const int swz = (bid & 7) * cpx + (bid >> 3);   // XCD k -> contiguous chunk k

    const int slot = (swz << 2) + (threadIdx.x >> 6);
    // slot>>5 is block-uniform (4 aligned consecutive slots never straddle a
    // 32-group); readfirstlane makes it provably uniform -> scalar loads.
    const int n    = __builtin_amdgcn_readfirstlane(order[slot >> 5]);
    const int p    = slot & (P_ - 1);             // wave-uniform
    const int lane = threadIdx.x & 63;
    const int bi   = __builtin_amdgcn_readfirstlane(batch_idx[n]);

    const float y1    = boxes[2 * n];
    const float y2    = boxes[2 * n + 1];
    const float bin_h = (y2 - y1) * (1.0f / (float)P_);
    const int   gh    = (int)ceilf(bin_h);

    const v4f* prow = (const v4f*)feat + (long)bi * (LV_ * (D_ / 4));  // scalar base

    v4f acc0 = {0.f, 0.f, 0.f, 0.f};
    v4f acc1 = {0.f, 0.f, 0.f, 0.f};

    if (gh >= 1) {
        const float cntf    = (float)gh;
        const float sub     = bin_h / cntf;
        const float inv_sub = 1.0f / sub;                  // huge/inf ok: n clamped, NaN killed by fmaxf
        const float halfsub = 0.5f * sub;
        const float boff    = (y1 - 0.5f) + (float)p * bin_h;
        const float a       = fmaf(0.5f, sub, boff);       // first sample
        const float ylast   = fmaf(cntf - 0.5f, sub, boff);

        int r_first = (int)floorf(a);                      // a >= -0.5 so floor >= -1
        if (r_first < 0) r_first = 0;
        if (r_first > LV_ - 1) r_first = LV_ - 1;
        int r_last = (int)floorf(ylast) + 1;
        if (r_last > LV_ - 1) r_last = LV_ - 1;
        if (r_last < r_first) r_last = r_first;

        // wave-uniform by construction -> force into SGPR loop counters
        const int r0 = __builtin_amdgcn_readfirstlane(r_first);
        const int rl = __builtin_amdgcn_readfirstlane(r_last);

        const float lanef = (float)lane;

        for (int base = r0; base <= rl; base += 64) {
            int kmax = rl - base; if (kmax > 63) kmax = 63; // valid rows 0..kmax
            const int full = (kmax + 1) & ~3;              // rows covered by 4-row groups
            const v4f* pA = prow + (long)base * (D_ / 4);  // scalar base, row base
            const v4f* pB = pA + 4 * (D_ / 4);             // scalar base, row base+4

            v4f A0, A1, A2, A3, B0, B1, B2, B3;

            // ---- prologue: issue up to 2 groups before the weight VALU ----
            if (full >= 4) { A0 = pA[lane]; A1 = pA[lane + 64]; A2 = pA[lane + 128]; A3 = pA[lane + 192]; }
            if (full >= 8) { B0 = pB[lane]; B1 = pB[lane + 64]; B2 = pB[lane + 128]; B3 = pB[lane + 192]; }

            // ---- lane-parallel weights (overlap prologue load latency) ----
            const int   r  = base + lane;
            const float d0 = ((float)base + lanef) - a;    // box-relative: good precision
            const float dm = d0 - 1.0f;
            const float dp = d0 + 1.0f;
            const float um = dm * inv_sub;
            const float u0 = d0 * inv_sub;
            const float up = dp * inv_sub;
            const float nm = fminf(fmaxf(ceilf(um), 0.0f), cntf);   // fmaxf eats NaN (0*inf)
            const float n0 = fminf(fmaxf(ceilf(u0), 0.0f), cntf);
            const float np = fminf(fmaxf(ceilf(up), 0.0f), cntf);
            float Pm = fmaf(nm, dm, -halfsub * fmaf(nm, nm, -nm));
            float P0 = fmaf(n0, d0, -halfsub * fmaf(n0, n0, -n0));
            float Pp = fmaf(np, dp, -halfsub * fmaf(np, np, -np));
            if (r == 0)       Pm = P0;                      // -> W(0) = P(1)-P(0)
            if (r == LV_ - 1) Pp = P0 + cntf;               // -> W(LV-1) = cnt + P(LV-2)-P(LV-1)
            const float Wl = (Pm + Pp) - 2.0f * P0;
            // lanes with r > kmax hold garbage W; never read (readlane idx <= kmax)

            // ---- steady: consume a group, immediately re-issue its next loads ----
            const v4f* qA = pA + 8 * (D_ / 4);              // row base+8,  scalar
            const v4f* qB = pB + 8 * (D_ / 4);              // row base+12, scalar
            int k = 0;
            while (k + 8 <= full) {
                acc0 += A0 * lane_bcast_f(Wl, k + 0);
                acc1 += A1 * lane_bcast_f(Wl, k + 1);
                acc0 += A2 * lane_bcast_f(Wl, k + 2);
                acc1 += A3 * lane_bcast_f(Wl, k + 3);
                if (k + 12 <= full) { A0 = qA[lane]; A1 = qA[lane + 64]; A2 = qA[lane + 128]; A3 = qA[lane + 192]; }
                acc0 += B0 * lane_bcast_f(Wl, k + 4);
                acc1 += B1 * lane_bcast_f(Wl, k + 5);
                acc0 += B2 * lane_bcast_f(Wl, k + 6);
                acc1 += B3 * lane_bcast_f(Wl, k + 7);
                if (k + 16 <= full) { B0 = qB[lane]; B1 = qB[lane + 64]; B2 = qB[lane + 128]; B3 = qB[lane + 192]; }
                qA += 8 * (D_ / 4); qB += 8 * (D_ / 4); k += 8;
            }
            if (k < full) {                                 // leftover 4-group sits in A
                acc0 += A0 * lane_bcast_f(Wl, k + 0);
                acc1 += A1 * lane_bcast_f(Wl, k + 1);
                acc0 += A2 * lane_bcast_f(Wl, k + 2);
                acc1 += A3 * lane_bcast_f(Wl, k + 3);
                k += 4;
            }
            // ---- tail <= 3 rows, scalar base + imm offsets ----
            const v4f* pT = prow + (long)(base + k) * (D_ / 4);
            if (k     <= kmax) acc0 += pT[lane]       * lane_bcast_f(Wl, k);
            if (k + 1 <= kmax) acc1 += pT[lane + 64]  * lane_bcast_f(Wl, k + 1);
            if (k + 2 <= kmax) acc0 += pT[lane + 128] * lane_bcast_f(Wl, k + 2);
        }
    }

    const float inv_c = 1.0f / (float)(gh > 1 ? gh : 1);
    v4f res = (acc0 + acc1) * inv_c;
    v4f* op = (v4f*)out + ((long)n * P_ + p) * (D_ / 4) + lane;
    __builtin_nontemporal_store(res, op);
}

extern "C" void kernel_launch(void* const* d_in, const int* in_sizes, int n_in,
                              void* d_out, int out_size, void* d_ws, size_t ws_size,
                              hipStream_t stream) {
    const float* feat      = (const float*)d_in[0];
    const float* boxes     = (const float*)d_in[1];
    const int*   batch_idx = (const int*)d_in[2];
    float*       out       = (float*)d_out;
    int*         order     = (int*)d_ws;    // N_ ints

    build_order_kernel<<<1, 256, 0, stream>>>(batch_idx, order);
    roi_rows_kernel<<<(N_ * P_) / 4, 256, 0, stream>>>(feat, boxes, batch_idx, order, out);
}